// Round 7
// baseline (674.391 us; speedup 1.0000x reference)
//
#include <hip/hip_runtime.h>
#include <math.h>

#define NC 8192
#define ID 512
#define HD 1024
#define OD 512
#define ED 128
#define NF 8
#define FS (NC/NF)   /* 1024 */
#define DC (FS/4)    /* 256 */

typedef __bf16 bf16x8 __attribute__((ext_vector_type(8)));
typedef float  f32x4  __attribute__((ext_vector_type(4)));

__device__ __forceinline__ float sigmf(float x){ return 1.0f/(1.0f+__expf(-x)); }

__device__ __forceinline__ unsigned short f2bf(float f){
  union { float f; unsigned u; } v; v.f = f;
  unsigned r = v.u + 0x7FFFu + ((v.u >> 16) & 1u);
  return (unsigned short)(r >> 16);
}
__device__ __forceinline__ float bf2f(unsigned short b){
  union { unsigned u; float f; } v; v.u = ((unsigned)b) << 16;
  return v.f;
}
__device__ __forceinline__ void gload16(const void* g, void* l){
  __builtin_amdgcn_global_load_lds(
      (const __attribute__((address_space(1))) unsigned int*)g,
      (__attribute__((address_space(3))) unsigned int*)l, 16, 0, 0);
}

// ---------------------------------------------------------------------------
// weight fp32 -> bf16 strided converter
__global__ __launch_bounds__(256) void k_conv(
    const float* __restrict__ src, unsigned short* __restrict__ dst,
    int rows, int cols, int sld, int sofs, int dld, float scale)
{
  int i = blockIdx.x*256 + threadIdx.x;
  int total = rows*cols/4;
  if (i >= total) return;
  int r = (i*4)/cols, c = (i*4)%cols;
  const float* s = src + (size_t)r*sld + sofs + c;
  unsigned long long pack = 0;
  for (int q=0;q<4;q++)
    pack |= (unsigned long long)f2bf(s[q]*scale) << (16*q);
  *reinterpret_cast<unsigned long long*>(&dst[(size_t)r*dld + c]) = pack;
}

// gate-cat GRU weights: dst[3][1024][1536] = [Wih_gate(512) | Whh_gate(1024)]
__global__ __launch_bounds__(256) void k_convgru(
    const float* __restrict__ Wih, const float* __restrict__ Whh,
    unsigned short* __restrict__ dst)
{
  int i = blockIdx.x*256 + threadIdx.x;         // group of 4
  const int total = 3*1024*1536/4;
  if (i >= total) return;
  int row = (i*4)/1536, c = (i*4)%1536;         // row = g*1024+n
  unsigned long long pack = 0;
  if (c < 512){
    const float* s = Wih + (size_t)row*(OD+1) + c;
    for (int q=0;q<4;q++) pack |= (unsigned long long)f2bf(s[q]) << (16*q);
  } else {
    const float* s = Whh + (size_t)row*HD + (c-512);
    for (int q=0;q<4;q++) pack |= (unsigned long long)f2bf(s[q]) << (16*q);
  }
  *reinterpret_cast<unsigned long long*>(&dst[(size_t)row*1536 + c]) = pack;
}

// ---------------------------------------------------------------------------
// K1: decohere features -> bf16 feat[NC][2HD]
__global__ __launch_bounds__(256) void k_feat(
    const float* __restrict__ rho_diag, const float* __restrict__ noise_diag,
    const float* __restrict__ rho_off,  const float* __restrict__ gamma,
    unsigned short* __restrict__ featb)
{
  int row = blockIdx.x;
  int t = threadIdx.x;
  float g = 1.0f/(1.0f+__expf(-gamma[0]));
  const float* rd = rho_diag  + (size_t)row*HD;
  const float* nd = noise_diag+ (size_t)row*HD;
  const float* ro = rho_off   + (size_t)row*HD;
  unsigned short* f0 = featb + (size_t)row*(2*HD);

  float v[4];
  float mx = -1e30f;
  for (int i=0;i<4;i++){ int j=t+i*256; v[i] = rd[j] + nd[j]*g*0.1f; mx = fmaxf(mx, v[i]); }
  __shared__ float red[256];
  red[t]=mx; __syncthreads();
  for(int s=128;s>0;s>>=1){ if(t<s) red[t]=fmaxf(red[t],red[t+s]); __syncthreads(); }
  mx = red[0]; __syncthreads();
  float sm=0.0f;
  for(int i=0;i<4;i++){ v[i]=__expf(v[i]-mx); sm+=v[i]; }
  red[t]=sm; __syncthreads();
  for(int s=128;s>0;s>>=1){ if(t<s) red[t]+=red[t+s]; __syncthreads(); }
  float inv = 1.0f/red[0];
  float om_g = 1.0f - g;
  for(int i=0;i<4;i++){
    int j=t+i*256;
    f0[j]     = f2bf(v[i]*inv);
    f0[HD+j]  = f2bf(fabsf(ro[j])*om_g);
  }
}

// ---------------------------------------------------------------------------
// MFMA bf16 GEMM: C[M,N] = A[M,K] @ W[N,K]^T, 128x128 tile, BK=32, 4 waves.
// n-major XCD chunking: each XCD chunk = few n-tiles x all m-tiles, so the
// weight slice stays L2-resident and A streams from L3.
// MODE 0: v = e0[m*N+n] + 0.1*(acc + e1[n]); write Cb only     (inj -> h bf16)
// MODE 1: v = relu(acc + e0[n]);            write Cb only      (engine hidden)
// MODE 2: v = acc + e0[n];                  write Cf + Cb      (out)
template<int MODE>
__global__ __launch_bounds__(256) void k_mgemm(
    const unsigned short* __restrict__ A, int lda,
    const unsigned short* __restrict__ W,
    int K, int N,
    float* __restrict__ Cf, int ldcf,
    unsigned short* __restrict__ Cb, int ldcb,
    const float* __restrict__ e0, const float* __restrict__ e1)
{
  __shared__ __attribute__((aligned(16))) unsigned short Asb[128*32];
  __shared__ __attribute__((aligned(16))) unsigned short Bsb[128*32];
  const int t = threadIdx.x;
  const int lane = t & 63, wid = t >> 6;
  const int wr = wid >> 1, wc = wid & 1;

  // XCD chunked swizzle, n-major chunks (all grids have nwg % 8 == 0)
  const int nwg = gridDim.x*gridDim.y;
  const int bid = blockIdx.y*gridDim.x + blockIdx.x;
  const int swz = (bid & 7)*(nwg >> 3) + (bid >> 3);
  const int n0 = (swz / gridDim.y) * 128, m0 = (swz % gridDim.y) * 128;

  const int srow = lane >> 2;
  const int skch = (lane & 3) * 8;
  const int fr = lane & 15, fk = (lane >> 4) * 8;

  f32x4 acc[4][4] = {};
  for (int k0 = 0; k0 < K; k0 += 32) {
    for (int q = 0; q < 2; ++q) {
      int r = wid*32 + q*16 + srow;
      gload16(A + (size_t)(m0 + r)*lda + k0 + skch, &Asb[(wid*32 + q*16)*32]);
      gload16(W + (size_t)(n0 + r)*K   + k0 + skch, &Bsb[(wid*32 + q*16)*32]);
    }
    __syncthreads();
    bf16x8 af[4], bfr[4];
    for (int i = 0; i < 4; ++i)
      af[i]  = *reinterpret_cast<const bf16x8*>(&Asb[(wr*64 + i*16 + fr)*32 + fk]);
    for (int j = 0; j < 4; ++j)
      bfr[j] = *reinterpret_cast<const bf16x8*>(&Bsb[(wc*64 + j*16 + fr)*32 + fk]);
    for (int i = 0; i < 4; ++i)
      for (int j = 0; j < 4; ++j)
        acc[i][j] = __builtin_amdgcn_mfma_f32_16x16x32_bf16(af[i], bfr[j], acc[i][j], 0, 0, 0);
    __syncthreads();
  }
  const int cr = (lane >> 4) * 4;
  const int cc = lane & 15;
  for (int i = 0; i < 4; ++i){
    for (int j = 0; j < 4; ++j){
      for (int r = 0; r < 4; ++r){
        int m = m0 + wr*64 + i*16 + cr + r;
        int n = n0 + wc*64 + j*16 + cc;
        float v = acc[i][j][r];
        if (MODE == 0)      v = e0[(size_t)m*N + n] + 0.1f*(v + e1[n]);
        else if (MODE == 1) v = fmaxf(v + e0[n], 0.0f);
        else if (MODE == 2) v = v + e0[n];
        if (MODE == 2) Cf[(size_t)m*ldcf + n] = v;
        Cb[(size_t)m*ldcb + n] = f2bf(v);
      }
    }
  }
}

// ---------------------------------------------------------------------------
// GRU megakernel v2: 128x128 tile, 8 waves (512 thr), BK=32.
// Acat[NC][1536] = [out(512) | h(1024)] bf16; Wg[3][1024][1536] gate-cat.
//   r  = sigm( gr + bih[n] + tens*wlast[n] + bhh[n] )
//   z  = sigm( gz + ... )
//   nn = tanh( gna + bih[2H+n] + tens*wlast[2H+n] + r*(gnb + bhh[2H+n]) )
//   newh = (1-z)*nn + z*h          (gna = K<512 part, gnb = K>=512 part)
__global__ __launch_bounds__(512) void k_gru_mega(
    const unsigned short* __restrict__ Acat,
    const unsigned short* __restrict__ Wg,
    const float* __restrict__ bih, const float* __restrict__ bhh,
    const float* __restrict__ tens, const float* __restrict__ wlast,
    float* __restrict__ newh)
{
  __shared__ __attribute__((aligned(16))) unsigned short As[128*32];
  __shared__ __attribute__((aligned(16))) unsigned short Rs[128*32];
  __shared__ __attribute__((aligned(16))) unsigned short Zs[128*32];
  __shared__ __attribute__((aligned(16))) unsigned short Ns[128*32];
  const int t = threadIdx.x;
  const int lane = t & 63, wid = t >> 6;         // 8 waves
  const int wr = wid >> 2, wc = wid & 3;         // 2 x 4 wave grid -> 64x32 per wave

  // n-major XCD chunking; grid (HD/128=8, NC/128=64) = 512 blocks
  const int nwg = gridDim.x*gridDim.y;
  const int bid = blockIdx.y*gridDim.x + blockIdx.x;
  const int swz = (bid & 7)*(nwg >> 3) + (bid >> 3);
  const int n0 = (swz / gridDim.y) * 128, m0 = (swz % gridDim.y) * 128;

  const int fr = lane & 15, fk = (lane >> 4) * 8;

  // staging: 2 waves per matrix; each wave: 4 issues of 16 rows
  const int mat = wid >> 1, v = wid & 1;
  const unsigned short* sbase;
  unsigned short* lbase;
  if      (mat == 0){ sbase = Acat + (size_t)m0*1536;            lbase = As; }
  else if (mat == 1){ sbase = Wg   + (size_t)n0*1536;            lbase = Rs; }
  else if (mat == 2){ sbase = Wg + (size_t)(HD   + n0)*1536;     lbase = Zs; }
  else              { sbase = Wg + (size_t)(2*HD + n0)*1536;     lbase = Ns; }
  const int srow = v*16 + (lane >> 2);           // row within 32-row group
  const int skch = (lane & 3) * 8;

  f32x4 acc_r[4][2] = {}, acc_z[4][2] = {}, acc_na[4][2] = {}, acc_nb[4][2] = {};

  for (int k0 = 0; k0 < 1536; k0 += 32) {
    #pragma unroll
    for (int p = 0; p < 4; ++p)
      gload16(sbase + (size_t)(p*32 + srow)*1536 + k0 + skch,
              &lbase[(p*32 + v*16)*32]);
    __syncthreads();
    bf16x8 af[4], br[2], bz[2], bn[2];
    #pragma unroll
    for (int i = 0; i < 4; ++i)
      af[i] = *reinterpret_cast<const bf16x8*>(&As[(wr*64 + i*16 + fr)*32 + fk]);
    #pragma unroll
    for (int j = 0; j < 2; ++j){
      br[j] = *reinterpret_cast<const bf16x8*>(&Rs[(wc*32 + j*16 + fr)*32 + fk]);
      bz[j] = *reinterpret_cast<const bf16x8*>(&Zs[(wc*32 + j*16 + fr)*32 + fk]);
      bn[j] = *reinterpret_cast<const bf16x8*>(&Ns[(wc*32 + j*16 + fr)*32 + fk]);
    }
    if (k0 < 512){
      #pragma unroll
      for (int i = 0; i < 4; ++i)
        #pragma unroll
        for (int j = 0; j < 2; ++j){
          acc_r [i][j] = __builtin_amdgcn_mfma_f32_16x16x32_bf16(af[i], br[j], acc_r [i][j], 0,0,0);
          acc_z [i][j] = __builtin_amdgcn_mfma_f32_16x16x32_bf16(af[i], bz[j], acc_z [i][j], 0,0,0);
          acc_na[i][j] = __builtin_amdgcn_mfma_f32_16x16x32_bf16(af[i], bn[j], acc_na[i][j], 0,0,0);
        }
    } else {
      #pragma unroll
      for (int i = 0; i < 4; ++i)
        #pragma unroll
        for (int j = 0; j < 2; ++j){
          acc_r [i][j] = __builtin_amdgcn_mfma_f32_16x16x32_bf16(af[i], br[j], acc_r [i][j], 0,0,0);
          acc_z [i][j] = __builtin_amdgcn_mfma_f32_16x16x32_bf16(af[i], bz[j], acc_z [i][j], 0,0,0);
          acc_nb[i][j] = __builtin_amdgcn_mfma_f32_16x16x32_bf16(af[i], bn[j], acc_nb[i][j], 0,0,0);
        }
    }
    __syncthreads();
  }

  const int cr = (lane >> 4) * 4;
  const int cc = lane & 15;
  for (int i = 0; i < 4; ++i){
    for (int r = 0; r < 4; ++r){
      int m = m0 + wr*64 + i*16 + cr + r;
      float tm = tens[m];
      for (int j = 0; j < 2; ++j){
        int n = n0 + wc*32 + j*16 + cc;
        float sr  = acc_r [i][j][r] + bih[n]      + tm*wlast[n]      + bhh[n];
        float sz  = acc_z [i][j][r] + bih[HD+n]   + tm*wlast[HD+n]   + bhh[HD+n];
        float sni = acc_na[i][j][r] + bih[2*HD+n] + tm*wlast[2*HD+n];
        float snh = acc_nb[i][j][r] + bhh[2*HD+n];
        float rg = sigmf(sr);
        float zg = sigmf(sz);
        float nn = tanhf(sni + rg*snh);
        float hv = bf2f(Acat[(size_t)m*1536 + 512 + n]);
        newh[(size_t)m*HD + n] = (1.0f - zg)*nn + zg*hv;
      }
    }
  }
}

// ---------------------------------------------------------------------------
__global__ __launch_bounds__(128) void k_xpart(
    const float* __restrict__ x,
    const float* __restrict__ aW1, const float* __restrict__ ab1,
    const float* __restrict__ gW1, const float* __restrict__ gb1,
    const float* __restrict__ Wih,
    const float* __restrict__ ab2, const float* __restrict__ gb2,
    float* __restrict__ xcat, float* __restrict__ wlast, float* __restrict__ b2diff)
{
  int t = threadIdx.x;
  if (blockIdx.x == 2){
    for (int n=t; n<3*HD; n+=128) wlast[n] = Wih[(size_t)n*(OD+1) + OD];
    for (int n=t; n<OD;   n+=128) b2diff[n] = ab2[n] - gb2[n];
    return;
  }
  const float* W = blockIdx.x ? gW1 : aW1;
  const float* b = blockIdx.x ? gb1 : ab1;
  float s = b[t];
  const float* wr = W + (size_t)t*(ID+HD);
  for (int k=0;k<ID;k++) s += x[k]*wr[k];
  xcat[blockIdx.x*ED + t] = s;
}

// ---------------------------------------------------------------------------
__global__ __launch_bounds__(256) void k_tension(
    const float* __restrict__ outp, float* __restrict__ tens)
{
  int m = blockIdx.x, t = threadIdx.x;
  float s = 0.0f;
  for (int j=t;j<OD;j+=256){ float v = outp[(size_t)m*OD + j]; s += v*v; }
  __shared__ float red[256];
  red[t]=s; __syncthreads();
  for(int k=128;k>0;k>>=1){ if(t<k) red[t]+=red[t+k]; __syncthreads(); }
  if (t==0) tens[m] = red[0] * (1.0f/OD);
}

// ---------------------------------------------------------------------------
__global__ __launch_bounds__(256) void k_fmean(
    const float* __restrict__ newh, float* __restrict__ fmean)
{
  int f = blockIdx.x;
  int j = blockIdx.y*256 + threadIdx.x;
  const float* base = newh + (size_t)f*FS*HD + j;
  float s = 0.0f;
  for (int c=0;c<FS;c++) s += base[(size_t)c*HD];
  fmean[f*HD + j] = s * (1.0f/FS);
}

__global__ __launch_bounds__(256) void k_sync(
    float* __restrict__ newh, const float* __restrict__ fmean,
    const int* __restrict__ step)
{
  size_t idx = (size_t)blockIdx.x*256 + threadIdx.x;
  int cell = (int)(idx / HD);
  int j    = (int)(idx % HD);
  int f = cell / FS, c = cell % FS;
  float v = newh[idx];
  v = 0.85f*v + 0.15f*fmean[f*HD + j];
  if (step[0] > 5 && c < DC){
    float glob = 0.0f;
    for (int ff=0; ff<NF; ff++) glob += fmean[ff*HD + j];
    glob *= (1.0f/NF);
    v = 0.85f*v + 0.15f*glob;
  }
  newh[idx] = v;
}

__global__ __launch_bounds__(1024) void k_wstats(
    const float* __restrict__ tens, float* __restrict__ stats)
{
  int t = threadIdx.x;
  float mx = -1e30f;
  for (int i=t;i<NC;i+=1024) mx = fmaxf(mx, tens[i]);
  __shared__ float red[1024];
  red[t]=mx; __syncthreads();
  for(int s=512;s>0;s>>=1){ if(t<s) red[t]=fmaxf(red[t],red[t+s]); __syncthreads(); }
  mx = red[0]; __syncthreads();
  float sm=0.0f;
  for (int i=t;i<NC;i+=1024) sm += __expf(tens[i]-mx);
  red[t]=sm; __syncthreads();
  for(int s=512;s>0;s>>=1){ if(t<s) red[t]+=red[t+s]; __syncthreads(); }
  if (t==0){ stats[0]=mx; stats[1]=red[0]; }
}

__global__ __launch_bounds__(256) void k_wnorm(
    const float* __restrict__ tens, const float* __restrict__ stats,
    float* __restrict__ w)
{
  int m = blockIdx.x*256 + threadIdx.x;
  w[m] = __expf(tens[m]-stats[0]) * (1.0f/stats[1]);
}

// combined stage 1: 64 blocks, each sums 128 rows (coalesced), writes partial[b][512]
__global__ __launch_bounds__(256) void k_comb1(
    const float* __restrict__ outp, const float* __restrict__ w,
    float* __restrict__ partial)
{
  int b = blockIdx.x, t = threadIdx.x;
  float a0 = 0.0f, a1 = 0.0f;
  for (int m = 0; m < 128; ++m){
    int row = b*128 + m;
    float wm = w[row];
    const float* r = outp + (size_t)row*OD;
    a0 += wm * r[t];
    a1 += wm * r[t+256];
  }
  partial[(size_t)b*OD + t]       = a0;
  partial[(size_t)b*OD + t + 256] = a1;
}

// combined stage 2: comb[n] = sum_b partial[b][n]
__global__ __launch_bounds__(256) void k_comb2(
    const float* __restrict__ partial, float* __restrict__ comb)
{
  int n = blockIdx.x*256 + threadIdx.x;
  float s = 0.0f;
  for (int b = 0; b < 64; ++b) s += partial[(size_t)b*OD + n];
  comb[n] = s;
}

__global__ __launch_bounds__(128) void k_pred(
    const float* __restrict__ comb, const float* __restrict__ headW,
    const float* __restrict__ headb, float* __restrict__ pred)
{
  int i = blockIdx.x, t = threadIdx.x;
  float s = 0.0f;
  const float* wr = headW + (size_t)i*OD;
  for (int k=t;k<OD;k+=128) s += comb[k]*wr[k];
  __shared__ float red[128];
  red[t]=s; __syncthreads();
  for (int sx=64;sx>0;sx>>=1){ if(t<sx) red[t]+=red[t+sx]; __syncthreads(); }
  if (t==0) pred[i] = red[0] + headb[i];
}

// ---------------------------------------------------------------------------
extern "C" void kernel_launch(void* const* d_in, const int* in_sizes, int n_in,
                              void* d_out, int out_size, void* d_ws, size_t ws_size,
                              hipStream_t stream)
{
  const float* x        = (const float*)d_in[0];
  const float* rho_diag = (const float*)d_in[1];
  const float* rho_off  = (const float*)d_in[2];
  const float* hiddens  = (const float*)d_in[3];
  const float* gamma    = (const float*)d_in[4];
  const float* proj_W   = (const float*)d_in[5];
  const float* proj_b   = (const float*)d_in[6];
  const float* a_W1     = (const float*)d_in[7];
  const float* a_b1     = (const float*)d_in[8];
  const float* a_W2     = (const float*)d_in[9];
  const float* a_b2     = (const float*)d_in[10];
  const float* g_W1     = (const float*)d_in[11];
  const float* g_b1     = (const float*)d_in[12];
  const float* g_W2     = (const float*)d_in[13];
  const float* g_b2     = (const float*)d_in[14];
  const float* gru_Wih  = (const float*)d_in[15];
  const float* gru_bih  = (const float*)d_in[16];
  const float* gru_Whh  = (const float*)d_in[17];
  const float* gru_bhh  = (const float*)d_in[18];
  const float* head_W   = (const float*)d_in[19];
  const float* head_b   = (const float*)d_in[20];
  const float* noise_d  = (const float*)d_in[21];
  const int*   step     = (const int*)d_in[23];

  float* pred = (float*)d_out;                  // [512]
  float* newh = (float*)d_out + ID;             // [NC*HD]

  char* ws = (char*)d_ws;
  const size_t MB = 1024*1024;
  unsigned short* Acat   = (unsigned short*)(ws + 0);        // [NC][1536] 24MB
  unsigned short* featb  = (unsigned short*)(ws + 24*MB);    // [NC][2048] 32MB
  float*          outp_f = (float*)(ws + 56*MB);             // [NC][512] 16MB
  unsigned short* eag    = (unsigned short*)(ws + 72*MB);    // [NC][256]  4MB
  unsigned short* wProj  = (unsigned short*)(ws + 76*MB);    // [1024][2048] 4MB
  unsigned short* wGru   = (unsigned short*)(ws + 80*MB);    // [3][1024][1536] 9MB
  unsigned short* wEng   = (unsigned short*)(ws + 89*MB);    // [256][1024] 0.5MB
  unsigned short* wW2    = (unsigned short*)(ws + 89*MB + 512*1024); // [512][256] 0.25MB
  char* sm = ws + 90*MB;
  float* tens    = (float*)(sm + 0);          // [NC]
  float* xcat    = (float*)(sm + 64*1024);    // [256]
  float* wlast   = (float*)(sm + 128*1024);   // [3HD]
  float* b2diff  = (float*)(sm + 160*1024);   // [OD]
  float* fmean   = (float*)(sm + 192*1024);   // [NF*HD]
  float* stats   = (float*)(sm + 256*1024);   // [2]
  float* wts     = (float*)(sm + 320*1024);   // [NC]
  float* partial = (float*)(sm + 384*1024);   // [64][512] 128KB
  float* comb    = (float*)(sm + 576*1024);   // [OD]

  dim3 blk(256);
  #define CONVGRID(n) dim3(((n)/4 + 255)/256)

  // weight conversions
  k_conv<<<CONVGRID(1024*2048), blk, 0, stream>>>(proj_W, wProj, 1024, 2048, 2048, 0, 2048, 1.0f);
  k_convgru<<<dim3(3*1024*1536/4/256), blk, 0, stream>>>(gru_Wih, gru_Whh, wGru);
  k_conv<<<CONVGRID(128*1024), blk, 0, stream>>>(a_W1, wEng,            128, 1024, ID+HD, ID, 1024, 1.0f);
  k_conv<<<CONVGRID(128*1024), blk, 0, stream>>>(g_W1, wEng + 128*1024, 128, 1024, ID+HD, ID, 1024, 1.0f);
  k_conv<<<CONVGRID(512*128),  blk, 0, stream>>>(a_W2, wW2,       512, 128, 128, 0, 256,  1.0f);
  k_conv<<<CONVGRID(512*128),  blk, 0, stream>>>(g_W2, wW2 + 128, 512, 128, 128, 0, 256, -1.0f);

  // feat + x-part
  k_feat<<<dim3(NC), blk, 0, stream>>>(rho_diag, noise_d, rho_off, gamma, featb);
  k_xpart<<<dim3(3), dim3(128), 0, stream>>>(x, a_W1, a_b1, g_W1, g_b1, gru_Wih,
                                             a_b2, g_b2, xcat, wlast, b2diff);

  // inj: h(bf16) = hiddens + 0.1*(feat@projW^T + b) -> Acat cols 512..1535
  k_mgemm<0><<<dim3(HD/128, NC/128), blk, 0, stream>>>(
      featb, 2*HD, wProj, 2*HD, HD, nullptr, 0, Acat + 512, 1536, hiddens, proj_b);
  // engine hidden: eag = relu(h@W1h^T + xcat)
  k_mgemm<1><<<dim3(256/128, NC/128), blk, 0, stream>>>(
      Acat + 512, 1536, wEng, HD, 256, nullptr, 0, eag, 256, xcat, nullptr);
  // out = eag@W2cat^T + (ab2-gb2) -> outp_f + Acat cols 0..511
  k_mgemm<2><<<dim3(OD/128, NC/128), blk, 0, stream>>>(
      eag, 256, wW2, 256, OD, outp_f, OD, Acat, 1536, b2diff, nullptr);
  // tension
  k_tension<<<dim3(NC), blk, 0, stream>>>(outp_f, tens);
  // fused gi+gh+GRU -> newh (128x128 tile, 8 waves)
  k_gru_mega<<<dim3(HD/128, NC/128), dim3(512), 0, stream>>>(
      Acat, wGru, gru_bih, gru_bhh, tens, wlast, newh);
  // faction sync
  k_fmean<<<dim3(NF, HD/256), blk, 0, stream>>>(newh, fmean);
  k_sync<<<dim3((NC*HD)/256), blk, 0, stream>>>(newh, fmean, step);
  // tension softmax -> combined -> pred
  k_wstats<<<dim3(1), dim3(1024), 0, stream>>>(tens, stats);
  k_wnorm<<<dim3(NC/256), blk, 0, stream>>>(tens, stats, wts);
  k_comb1<<<dim3(64), blk, 0, stream>>>(outp_f, wts, partial);
  k_comb2<<<dim3(2), blk, 0, stream>>>(partial, comb);
  k_pred<<<dim3(ID), dim3(128), 0, stream>>>(comb, head_W, head_b, pred);
}

// Round 8
// 591.723 us; speedup vs baseline: 1.1397x; 1.1397x over previous
//
#include <hip/hip_runtime.h>
#include <math.h>

#define NC 8192
#define ID 512
#define HD 1024
#define OD 512
#define ED 128
#define NF 8
#define FS (NC/NF)   /* 1024 */
#define DC (FS/4)    /* 256 */

typedef __bf16 bf16x8 __attribute__((ext_vector_type(8)));
typedef float  f32x4  __attribute__((ext_vector_type(4)));

__device__ __forceinline__ float sigmf(float x){ return 1.0f/(1.0f+__expf(-x)); }

__device__ __forceinline__ unsigned short f2bf(float f){
  union { float f; unsigned u; } v; v.f = f;
  unsigned r = v.u + 0x7FFFu + ((v.u >> 16) & 1u);
  return (unsigned short)(r >> 16);
}
__device__ __forceinline__ float bf2f(unsigned short b){
  union { unsigned u; float f; } v; v.u = ((unsigned)b) << 16;
  return v.f;
}
__device__ __forceinline__ void gload16(const void* g, void* l){
  __builtin_amdgcn_global_load_lds(
      (const __attribute__((address_space(1))) unsigned int*)g,
      (__attribute__((address_space(3))) unsigned int*)l, 16, 0, 0);
}

// ---------------------------------------------------------------------------
// weight fp32 -> bf16 strided converter
__global__ __launch_bounds__(256) void k_conv(
    const float* __restrict__ src, unsigned short* __restrict__ dst,
    int rows, int cols, int sld, int sofs, int dld, float scale)
{
  int i = blockIdx.x*256 + threadIdx.x;
  int total = rows*cols/4;
  if (i >= total) return;
  int r = (i*4)/cols, c = (i*4)%cols;
  const float* s = src + (size_t)r*sld + sofs + c;
  unsigned long long pack = 0;
  for (int q=0;q<4;q++)
    pack |= (unsigned long long)f2bf(s[q]*scale) << (16*q);
  *reinterpret_cast<unsigned long long*>(&dst[(size_t)r*dld + c]) = pack;
}

// gate-cat GRU weights: dst[3][1024][1536] = [Wih_gate(512) | Whh_gate(1024)]
__global__ __launch_bounds__(256) void k_convgru(
    const float* __restrict__ Wih, const float* __restrict__ Whh,
    unsigned short* __restrict__ dst)
{
  int i = blockIdx.x*256 + threadIdx.x;         // group of 4
  const int total = 3*1024*1536/4;
  if (i >= total) return;
  int row = (i*4)/1536, c = (i*4)%1536;         // row = g*1024+n
  unsigned long long pack = 0;
  if (c < 512){
    const float* s = Wih + (size_t)row*(OD+1) + c;
    for (int q=0;q<4;q++) pack |= (unsigned long long)f2bf(s[q]) << (16*q);
  } else {
    const float* s = Whh + (size_t)row*HD + (c-512);
    for (int q=0;q<4;q++) pack |= (unsigned long long)f2bf(s[q]) << (16*q);
  }
  *reinterpret_cast<unsigned long long*>(&dst[(size_t)row*1536 + c]) = pack;
}

// ---------------------------------------------------------------------------
// K1: decohere features -> bf16 feat[NC][2HD]
__global__ __launch_bounds__(256) void k_feat(
    const float* __restrict__ rho_diag, const float* __restrict__ noise_diag,
    const float* __restrict__ rho_off,  const float* __restrict__ gamma,
    unsigned short* __restrict__ featb)
{
  int row = blockIdx.x;
  int t = threadIdx.x;
  float g = 1.0f/(1.0f+__expf(-gamma[0]));
  const float* rd = rho_diag  + (size_t)row*HD;
  const float* nd = noise_diag+ (size_t)row*HD;
  const float* ro = rho_off   + (size_t)row*HD;
  unsigned short* f0 = featb + (size_t)row*(2*HD);

  float v[4];
  float mx = -1e30f;
  for (int i=0;i<4;i++){ int j=t+i*256; v[i] = rd[j] + nd[j]*g*0.1f; mx = fmaxf(mx, v[i]); }
  __shared__ float red[256];
  red[t]=mx; __syncthreads();
  for(int s=128;s>0;s>>=1){ if(t<s) red[t]=fmaxf(red[t],red[t+s]); __syncthreads(); }
  mx = red[0]; __syncthreads();
  float sm=0.0f;
  for(int i=0;i<4;i++){ v[i]=__expf(v[i]-mx); sm+=v[i]; }
  red[t]=sm; __syncthreads();
  for(int s=128;s>0;s>>=1){ if(t<s) red[t]+=red[t+s]; __syncthreads(); }
  float inv = 1.0f/red[0];
  float om_g = 1.0f - g;
  for(int i=0;i<4;i++){
    int j=t+i*256;
    f0[j]     = f2bf(v[i]*inv);
    f0[HD+j]  = f2bf(fabsf(ro[j])*om_g);
  }
}

// ---------------------------------------------------------------------------
// MFMA bf16 GEMM: C[M,N] = A[M,K] @ W[N,K]^T, 128x128 tile, BK=32, 4 waves,
// LDS double-buffer (one barrier per K-step), n-major XCD chunking.
// MODE 0: v = e0[m*N+n] + 0.1*(acc + e1[n]); write Cb only     (inj -> h bf16)
// MODE 1: v = relu(acc + e0[n]);            write Cb only      (engine hidden)
// MODE 2: v = acc + e0[n];                  write Cf + Cb      (out)
template<int MODE>
__global__ __launch_bounds__(256) void k_mgemm(
    const unsigned short* __restrict__ A, int lda,
    const unsigned short* __restrict__ W,
    int K, int N,
    float* __restrict__ Cf, int ldcf,
    unsigned short* __restrict__ Cb, int ldcb,
    const float* __restrict__ e0, const float* __restrict__ e1)
{
  __shared__ __attribute__((aligned(16))) unsigned short Asb[2][128*32];
  __shared__ __attribute__((aligned(16))) unsigned short Bsb[2][128*32];
  const int t = threadIdx.x;
  const int lane = t & 63, wid = t >> 6;
  const int wr = wid >> 1, wc = wid & 1;

  // n-major XCD chunked swizzle (all grids have nwg % 8 == 0)
  const int nwg = gridDim.x*gridDim.y;
  const int bid = blockIdx.y*gridDim.x + blockIdx.x;
  const int swz = (bid & 7)*(nwg >> 3) + (bid >> 3);
  const int n0 = (swz / gridDim.y) * 128, m0 = (swz % gridDim.y) * 128;

  const int srow = lane >> 2;
  const int skch = (lane & 3) * 8;
  const int fr = lane & 15, fk = (lane >> 4) * 8;

  const int nk = K >> 5;
  f32x4 acc[4][4] = {};

  // prologue stage
  {
    for (int q = 0; q < 2; ++q) {
      int r = wid*32 + q*16 + srow;
      gload16(A + (size_t)(m0 + r)*lda + skch, &Asb[0][(wid*32 + q*16)*32]);
      gload16(W + (size_t)(n0 + r)*K   + skch, &Bsb[0][(wid*32 + q*16)*32]);
    }
  }
  __syncthreads();

  for (int kk = 0; kk < nk; ++kk) {
    const int buf = kk & 1;
    if (kk + 1 < nk) {
      const int k0 = (kk + 1) << 5;
      for (int q = 0; q < 2; ++q) {
        int r = wid*32 + q*16 + srow;
        gload16(A + (size_t)(m0 + r)*lda + k0 + skch, &Asb[buf^1][(wid*32 + q*16)*32]);
        gload16(W + (size_t)(n0 + r)*K   + k0 + skch, &Bsb[buf^1][(wid*32 + q*16)*32]);
      }
    }
    bf16x8 af[4], bfr[4];
    for (int i = 0; i < 4; ++i)
      af[i]  = *reinterpret_cast<const bf16x8*>(&Asb[buf][(wr*64 + i*16 + fr)*32 + fk]);
    for (int j = 0; j < 4; ++j)
      bfr[j] = *reinterpret_cast<const bf16x8*>(&Bsb[buf][(wc*64 + j*16 + fr)*32 + fk]);
    for (int i = 0; i < 4; ++i)
      for (int j = 0; j < 4; ++j)
        acc[i][j] = __builtin_amdgcn_mfma_f32_16x16x32_bf16(af[i], bfr[j], acc[i][j], 0, 0, 0);
    __syncthreads();
  }

  const int cr = (lane >> 4) * 4;
  const int cc = lane & 15;
  for (int i = 0; i < 4; ++i){
    for (int j = 0; j < 4; ++j){
      for (int r = 0; r < 4; ++r){
        int m = m0 + wr*64 + i*16 + cr + r;
        int n = n0 + wc*64 + j*16 + cc;
        float v = acc[i][j][r];
        if (MODE == 0)      v = e0[(size_t)m*N + n] + 0.1f*(v + e1[n]);
        else if (MODE == 1) v = fmaxf(v + e0[n], 0.0f);
        else if (MODE == 2) v = v + e0[n];
        if (MODE == 2) Cf[(size_t)m*ldcf + n] = v;
        Cb[(size_t)m*ldcb + n] = f2bf(v);
      }
    }
  }
}

// ---------------------------------------------------------------------------
// GRU megakernel (v1 shape + dbuf + n-major): 64x64 tile, 4 waves, BK=32.
// Acat[NC][1536] = [out(512) | h(1024)] bf16; Wg[3][1024][1536] gate-cat.
//   r  = sigm( gr + bih[n] + tens*wlast[n] + bhh[n] )
//   z  = sigm( gz + ... )
//   nn = tanh( gna + bih[2H+n] + tens*wlast[2H+n] + r*(gnb + bhh[2H+n]) )
//   newh = (1-z)*nn + z*h          (gna = K<512 part, gnb = K>=512 part)
__global__ __launch_bounds__(256) void k_gru_mega(
    const unsigned short* __restrict__ Acat,
    const unsigned short* __restrict__ Wg,
    const float* __restrict__ bih, const float* __restrict__ bhh,
    const float* __restrict__ tens, const float* __restrict__ wlast,
    float* __restrict__ newh)
{
  __shared__ __attribute__((aligned(16))) unsigned short As[2][64*32];
  __shared__ __attribute__((aligned(16))) unsigned short Rs[2][64*32];
  __shared__ __attribute__((aligned(16))) unsigned short Zs[2][64*32];
  __shared__ __attribute__((aligned(16))) unsigned short Ns[2][64*32];
  const int t = threadIdx.x;
  const int lane = t & 63, wid = t >> 6;
  const int wr = wid >> 1, wc = wid & 1;

  // n-major XCD chunking; grid (HD/64=16, NC/64=128) = 2048 blocks.
  // chunk = 256 blocks = 2 n-tiles x 128 m-tiles -> weight slice 1.18MB (L2-fit)
  const int nwg = gridDim.x*gridDim.y;
  const int bid = blockIdx.y*gridDim.x + blockIdx.x;
  const int swz = (bid & 7)*(nwg >> 3) + (bid >> 3);
  const int n0 = (swz / gridDim.y) * 64, m0 = (swz % gridDim.y) * 64;

  const int srow = lane >> 2;          // 0..15
  const int skch = (lane & 3) * 8;
  const int fr = lane & 15, fk = (lane >> 4) * 8;

  // wave w stages matrix w (A, Wr, Wz, Wn)
  const unsigned short* sbase;
  unsigned short* lb0; unsigned short* lb1;
  if      (wid == 0){ sbase = Acat + (size_t)m0*1536;          lb0 = As[0]; lb1 = As[1]; }
  else if (wid == 1){ sbase = Wg   + (size_t)n0*1536;          lb0 = Rs[0]; lb1 = Rs[1]; }
  else if (wid == 2){ sbase = Wg + (size_t)(HD   + n0)*1536;   lb0 = Zs[0]; lb1 = Zs[1]; }
  else              { sbase = Wg + (size_t)(2*HD + n0)*1536;   lb0 = Ns[0]; lb1 = Ns[1]; }

  f32x4 acc_r[2][2] = {}, acc_z[2][2] = {}, acc_na[2][2] = {}, acc_nb[2][2] = {};

  // prologue stage (k0 = 0 -> buf 0)
  #pragma unroll
  for (int q = 0; q < 4; ++q)
    gload16(sbase + (size_t)(q*16 + srow)*1536 + skch, &lb0[(q*16)*32]);
  __syncthreads();

  for (int kk = 0; kk < 48; ++kk) {
    const int buf = kk & 1;
    if (kk < 47) {
      const int k0 = (kk + 1) << 5;
      unsigned short* lb = buf ? lb0 : lb1;
      #pragma unroll
      for (int q = 0; q < 4; ++q)
        gload16(sbase + (size_t)(q*16 + srow)*1536 + k0 + skch, &lb[(q*16)*32]);
    }
    bf16x8 af[2], br[2], bz[2], bn[2];
    #pragma unroll
    for (int i = 0; i < 2; ++i)
      af[i] = *reinterpret_cast<const bf16x8*>(&As[buf][(wr*32 + i*16 + fr)*32 + fk]);
    #pragma unroll
    for (int j = 0; j < 2; ++j){
      br[j] = *reinterpret_cast<const bf16x8*>(&Rs[buf][(wc*32 + j*16 + fr)*32 + fk]);
      bz[j] = *reinterpret_cast<const bf16x8*>(&Zs[buf][(wc*32 + j*16 + fr)*32 + fk]);
      bn[j] = *reinterpret_cast<const bf16x8*>(&Ns[buf][(wc*32 + j*16 + fr)*32 + fk]);
    }
    if (kk < 16){
      #pragma unroll
      for (int i = 0; i < 2; ++i)
        #pragma unroll
        for (int j = 0; j < 2; ++j){
          acc_r [i][j] = __builtin_amdgcn_mfma_f32_16x16x32_bf16(af[i], br[j], acc_r [i][j], 0,0,0);
          acc_z [i][j] = __builtin_amdgcn_mfma_f32_16x16x32_bf16(af[i], bz[j], acc_z [i][j], 0,0,0);
          acc_na[i][j] = __builtin_amdgcn_mfma_f32_16x16x32_bf16(af[i], bn[j], acc_na[i][j], 0,0,0);
        }
    } else {
      #pragma unroll
      for (int i = 0; i < 2; ++i)
        #pragma unroll
        for (int j = 0; j < 2; ++j){
          acc_r [i][j] = __builtin_amdgcn_mfma_f32_16x16x32_bf16(af[i], br[j], acc_r [i][j], 0,0,0);
          acc_z [i][j] = __builtin_amdgcn_mfma_f32_16x16x32_bf16(af[i], bz[j], acc_z [i][j], 0,0,0);
          acc_nb[i][j] = __builtin_amdgcn_mfma_f32_16x16x32_bf16(af[i], bn[j], acc_nb[i][j], 0,0,0);
        }
    }
    __syncthreads();
  }

  const int cr = (lane >> 4) * 4;
  const int cc = lane & 15;
  for (int i = 0; i < 2; ++i){
    for (int r = 0; r < 4; ++r){
      int m = m0 + wr*32 + i*16 + cr + r;
      float tm = tens[m];
      for (int j = 0; j < 2; ++j){
        int n = n0 + wc*32 + j*16 + cc;
        float sr  = acc_r [i][j][r] + bih[n]      + tm*wlast[n]      + bhh[n];
        float sz  = acc_z [i][j][r] + bih[HD+n]   + tm*wlast[HD+n]   + bhh[HD+n];
        float sni = acc_na[i][j][r] + bih[2*HD+n] + tm*wlast[2*HD+n];
        float snh = acc_nb[i][j][r] + bhh[2*HD+n];
        float rg = sigmf(sr);
        float zg = sigmf(sz);
        float nn = tanhf(sni + rg*snh);
        float hv = bf2f(Acat[(size_t)m*1536 + 512 + n]);
        newh[(size_t)m*HD + n] = (1.0f - zg)*nn + zg*hv;
      }
    }
  }
}

// ---------------------------------------------------------------------------
__global__ __launch_bounds__(128) void k_xpart(
    const float* __restrict__ x,
    const float* __restrict__ aW1, const float* __restrict__ ab1,
    const float* __restrict__ gW1, const float* __restrict__ gb1,
    const float* __restrict__ Wih,
    const float* __restrict__ ab2, const float* __restrict__ gb2,
    float* __restrict__ xcat, float* __restrict__ wlast, float* __restrict__ b2diff)
{
  int t = threadIdx.x;
  if (blockIdx.x == 2){
    for (int n=t; n<3*HD; n+=128) wlast[n] = Wih[(size_t)n*(OD+1) + OD];
    for (int n=t; n<OD;   n+=128) b2diff[n] = ab2[n] - gb2[n];
    return;
  }
  const float* W = blockIdx.x ? gW1 : aW1;
  const float* b = blockIdx.x ? gb1 : ab1;
  float s = b[t];
  const float* wr = W + (size_t)t*(ID+HD);
  for (int k=0;k<ID;k++) s += x[k]*wr[k];
  xcat[blockIdx.x*ED + t] = s;
}

// ---------------------------------------------------------------------------
__global__ __launch_bounds__(256) void k_tension(
    const float* __restrict__ outp, float* __restrict__ tens)
{
  int m = blockIdx.x, t = threadIdx.x;
  float s = 0.0f;
  for (int j=t;j<OD;j+=256){ float v = outp[(size_t)m*OD + j]; s += v*v; }
  __shared__ float red[256];
  red[t]=s; __syncthreads();
  for(int k=128;k>0;k>>=1){ if(t<k) red[t]+=red[t+k]; __syncthreads(); }
  if (t==0) tens[m] = red[0] * (1.0f/OD);
}

// ---------------------------------------------------------------------------
__global__ __launch_bounds__(256) void k_fmean(
    const float* __restrict__ newh, float* __restrict__ fmean)
{
  int f = blockIdx.x;
  int j = blockIdx.y*256 + threadIdx.x;
  const float* base = newh + (size_t)f*FS*HD + j;
  float s = 0.0f;
  for (int c=0;c<FS;c++) s += base[(size_t)c*HD];
  fmean[f*HD + j] = s * (1.0f/FS);
}

__global__ __launch_bounds__(256) void k_sync(
    float* __restrict__ newh, const float* __restrict__ fmean,
    const int* __restrict__ step)
{
  size_t idx = (size_t)blockIdx.x*256 + threadIdx.x;
  int cell = (int)(idx / HD);
  int j    = (int)(idx % HD);
  int f = cell / FS, c = cell % FS;
  float v = newh[idx];
  v = 0.85f*v + 0.15f*fmean[f*HD + j];
  if (step[0] > 5 && c < DC){
    float glob = 0.0f;
    for (int ff=0; ff<NF; ff++) glob += fmean[ff*HD + j];
    glob *= (1.0f/NF);
    v = 0.85f*v + 0.15f*glob;
  }
  newh[idx] = v;
}

__global__ __launch_bounds__(1024) void k_wstats(
    const float* __restrict__ tens, float* __restrict__ stats)
{
  int t = threadIdx.x;
  float mx = -1e30f;
  for (int i=t;i<NC;i+=1024) mx = fmaxf(mx, tens[i]);
  __shared__ float red[1024];
  red[t]=mx; __syncthreads();
  for(int s=512;s>0;s>>=1){ if(t<s) red[t]=fmaxf(red[t],red[t+s]); __syncthreads(); }
  mx = red[0]; __syncthreads();
  float sm=0.0f;
  for (int i=t;i<NC;i+=1024) sm += __expf(tens[i]-mx);
  red[t]=sm; __syncthreads();
  for(int s=512;s>0;s>>=1){ if(t<s) red[t]+=red[t+s]; __syncthreads(); }
  if (t==0){ stats[0]=mx; stats[1]=red[0]; }
}

__global__ __launch_bounds__(256) void k_wnorm(
    const float* __restrict__ tens, const float* __restrict__ stats,
    float* __restrict__ w)
{
  int m = blockIdx.x*256 + threadIdx.x;
  w[m] = __expf(tens[m]-stats[0]) * (1.0f/stats[1]);
}

// combined stage 1: 64 blocks, each sums 128 rows (coalesced), writes partial[b][512]
__global__ __launch_bounds__(256) void k_comb1(
    const float* __restrict__ outp, const float* __restrict__ w,
    float* __restrict__ partial)
{
  int b = blockIdx.x, t = threadIdx.x;
  float a0 = 0.0f, a1 = 0.0f;
  for (int m = 0; m < 128; ++m){
    int row = b*128 + m;
    float wm = w[row];
    const float* r = outp + (size_t)row*OD;
    a0 += wm * r[t];
    a1 += wm * r[t+256];
  }
  partial[(size_t)b*OD + t]       = a0;
  partial[(size_t)b*OD + t + 256] = a1;
}

// combined stage 2: comb[n] = sum_b partial[b][n]
__global__ __launch_bounds__(256) void k_comb2(
    const float* __restrict__ partial, float* __restrict__ comb)
{
  int n = blockIdx.x*256 + threadIdx.x;
  float s = 0.0f;
  for (int b = 0; b < 64; ++b) s += partial[(size_t)b*OD + n];
  comb[n] = s;
}

__global__ __launch_bounds__(128) void k_pred(
    const float* __restrict__ comb, const float* __restrict__ headW,
    const float* __restrict__ headb, float* __restrict__ pred)
{
  int i = blockIdx.x, t = threadIdx.x;
  float s = 0.0f;
  const float* wr = headW + (size_t)i*OD;
  for (int k=t;k<OD;k+=128) s += comb[k]*wr[k];
  __shared__ float red[128];
  red[t]=s; __syncthreads();
  for (int sx=64;sx>0;sx>>=1){ if(t<sx) red[t]+=red[t+sx]; __syncthreads(); }
  if (t==0) pred[i] = red[0] + headb[i];
}

// ---------------------------------------------------------------------------
extern "C" void kernel_launch(void* const* d_in, const int* in_sizes, int n_in,
                              void* d_out, int out_size, void* d_ws, size_t ws_size,
                              hipStream_t stream)
{
  const float* x        = (const float*)d_in[0];
  const float* rho_diag = (const float*)d_in[1];
  const float* rho_off  = (const float*)d_in[2];
  const float* hiddens  = (const float*)d_in[3];
  const float* gamma    = (const float*)d_in[4];
  const float* proj_W   = (const float*)d_in[5];
  const float* proj_b   = (const float*)d_in[6];
  const float* a_W1     = (const float*)d_in[7];
  const float* a_b1     = (const float*)d_in[8];
  const float* a_W2     = (const float*)d_in[9];
  const float* a_b2     = (const float*)d_in[10];
  const float* g_W1     = (const float*)d_in[11];
  const float* g_b1     = (const float*)d_in[12];
  const float* g_W2     = (const float*)d_in[13];
  const float* g_b2     = (const float*)d_in[14];
  const float* gru_Wih  = (const float*)d_in[15];
  const float* gru_bih  = (const float*)d_in[16];
  const float* gru_Whh  = (const float*)d_in[17];
  const float* gru_bhh  = (const float*)d_in[18];
  const float* head_W   = (const float*)d_in[19];
  const float* head_b   = (const float*)d_in[20];
  const float* noise_d  = (const float*)d_in[21];
  const int*   step     = (const int*)d_in[23];

  float* pred = (float*)d_out;                  // [512]
  float* newh = (float*)d_out + ID;             // [NC*HD]

  char* ws = (char*)d_ws;
  const size_t MB = 1024*1024;
  unsigned short* Acat   = (unsigned short*)(ws + 0);        // [NC][1536] 24MB
  unsigned short* featb  = (unsigned short*)(ws + 24*MB);    // [NC][2048] 32MB
  float*          outp_f = (float*)(ws + 56*MB);             // [NC][512] 16MB
  unsigned short* eag    = (unsigned short*)(ws + 72*MB);    // [NC][256]  4MB
  unsigned short* wProj  = (unsigned short*)(ws + 76*MB);    // [1024][2048] 4MB
  unsigned short* wGru   = (unsigned short*)(ws + 80*MB);    // [3][1024][1536] 9MB
  unsigned short* wEng   = (unsigned short*)(ws + 89*MB);    // [256][1024] 0.5MB
  unsigned short* wW2    = (unsigned short*)(ws + 89*MB + 512*1024); // [512][256] 0.25MB
  char* sm = ws + 90*MB;
  float* tens    = (float*)(sm + 0);          // [NC]
  float* xcat    = (float*)(sm + 64*1024);    // [256]
  float* wlast   = (float*)(sm + 128*1024);   // [3HD]
  float* b2diff  = (float*)(sm + 160*1024);   // [OD]
  float* fmean   = (float*)(sm + 192*1024);   // [NF*HD]
  float* stats   = (float*)(sm + 256*1024);   // [2]
  float* wts     = (float*)(sm + 320*1024);   // [NC]
  float* partial = (float*)(sm + 384*1024);   // [64][512] 128KB
  float* comb    = (float*)(sm + 576*1024);   // [OD]

  dim3 blk(256);
  #define CONVGRID(n) dim3(((n)/4 + 255)/256)

  // weight conversions
  k_conv<<<CONVGRID(1024*2048), blk, 0, stream>>>(proj_W, wProj, 1024, 2048, 2048, 0, 2048, 1.0f);
  k_convgru<<<dim3(3*1024*1536/4/256), blk, 0, stream>>>(gru_Wih, gru_Whh, wGru);
  k_conv<<<CONVGRID(128*1024), blk, 0, stream>>>(a_W1, wEng,            128, 1024, ID+HD, ID, 1024, 1.0f);
  k_conv<<<CONVGRID(128*1024), blk, 0, stream>>>(g_W1, wEng + 128*1024, 128, 1024, ID+HD, ID, 1024, 1.0f);
  k_conv<<<CONVGRID(512*128),  blk, 0, stream>>>(a_W2, wW2,       512, 128, 128, 0, 256,  1.0f);
  k_conv<<<CONVGRID(512*128),  blk, 0, stream>>>(g_W2, wW2 + 128, 512, 128, 128, 0, 256, -1.0f);

  // feat + x-part
  k_feat<<<dim3(NC), blk, 0, stream>>>(rho_diag, noise_d, rho_off, gamma, featb);
  k_xpart<<<dim3(3), dim3(128), 0, stream>>>(x, a_W1, a_b1, g_W1, g_b1, gru_Wih,
                                             a_b2, g_b2, xcat, wlast, b2diff);

  // inj: h(bf16) = hiddens + 0.1*(feat@projW^T + b) -> Acat cols 512..1535
  k_mgemm<0><<<dim3(HD/128, NC/128), blk, 0, stream>>>(
      featb, 2*HD, wProj, 2*HD, HD, nullptr, 0, Acat + 512, 1536, hiddens, proj_b);
  // engine hidden: eag = relu(h@W1h^T + xcat)
  k_mgemm<1><<<dim3(256/128, NC/128), blk, 0, stream>>>(
      Acat + 512, 1536, wEng, HD, 256, nullptr, 0, eag, 256, xcat, nullptr);
  // out = eag@W2cat^T + (ab2-gb2) -> outp_f + Acat cols 0..511
  k_mgemm<2><<<dim3(OD/128, NC/128), blk, 0, stream>>>(
      eag, 256, wW2, 256, OD, outp_f, OD, Acat, 1536, b2diff, nullptr);
  // tension
  k_tension<<<dim3(NC), blk, 0, stream>>>(outp_f, tens);
  // fused gi+gh+GRU -> newh (64x64 tile, 4 waves, dbuf)
  k_gru_mega<<<dim3(HD/64, NC/64), blk, 0, stream>>>(
      Acat, wGru, gru_bih, gru_bhh, tens, wlast, newh);
  // faction sync
  k_fmean<<<dim3(NF, HD/256), blk, 0, stream>>>(newh, fmean);
  k_sync<<<dim3((NC*HD)/256), blk, 0, stream>>>(newh, fmean, step);
  // tension softmax -> combined -> pred
  k_wstats<<<dim3(1), dim3(1024), 0, stream>>>(tens, stats);
  k_wnorm<<<dim3(NC/256), blk, 0, stream>>>(tens, stats, wts);
  k_comb1<<<dim3(64), blk, 0, stream>>>(outp_f, wts, partial);
  k_comb2<<<dim3(2), blk, 0, stream>>>(partial, comb);
  k_pred<<<dim3(ID), dim3(128), 0, stream>>>(comb, head_W, head_b, pred);
}

// Round 9
// 579.114 us; speedup vs baseline: 1.1645x; 1.0218x over previous
//
#include <hip/hip_runtime.h>
#include <math.h>

#define NC 8192
#define ID 512
#define HD 1024
#define OD 512
#define ED 128
#define NF 8
#define FS (NC/NF)   /* 1024 */
#define DC (FS/4)    /* 256 */

typedef __bf16 bf16x8 __attribute__((ext_vector_type(8)));
typedef float  f32x4  __attribute__((ext_vector_type(4)));

__device__ __forceinline__ float sigmf(float x){ return 1.0f/(1.0f+__expf(-x)); }

__device__ __forceinline__ unsigned short f2bf(float f){
  union { float f; unsigned u; } v; v.f = f;
  unsigned r = v.u + 0x7FFFu + ((v.u >> 16) & 1u);
  return (unsigned short)(r >> 16);
}
__device__ __forceinline__ float bf2f(unsigned short b){
  union { unsigned u; float f; } v; v.u = ((unsigned)b) << 16;
  return v.f;
}
__device__ __forceinline__ void gload16(const void* g, void* l){
  __builtin_amdgcn_global_load_lds(
      (const __attribute__((address_space(1))) unsigned int*)g,
      (__attribute__((address_space(3))) unsigned int*)l, 16, 0, 0);
}
__device__ __forceinline__ void pack4(const float* s, unsigned short* d, float sc){
  unsigned long long p = 0;
  for (int q=0;q<4;q++) p |= (unsigned long long)f2bf(s[q]*sc) << (16*q);
  *reinterpret_cast<unsigned long long*>(d) = p;
}

#define WAIT_VM4()  asm volatile("s_waitcnt vmcnt(4)" ::: "memory")
#define WAIT_VM0()  asm volatile("s_waitcnt vmcnt(0)" ::: "memory")
#define BARRIER()   do { __builtin_amdgcn_s_barrier(); asm volatile("" ::: "memory"); } while(0)

// ---------------------------------------------------------------------------
// k_prep: all weight fp32->bf16 conversions + xcat + wlast + b2diff, 1 launch.
// blocks: [0,2048) proj | [2048,6656) gruCat | [6656,6784) aW1h | [6784,6912) gW1h
//         [6912,6976) aW2 | [6976,7040) gW2 | 7040 xcat | 7041 wlast+b2diff
__global__ __launch_bounds__(256) void k_prep(
    const float* __restrict__ proj_W, const float* __restrict__ Wih,
    const float* __restrict__ Whh,
    const float* __restrict__ aW1, const float* __restrict__ gW1,
    const float* __restrict__ aW2, const float* __restrict__ gW2,
    const float* __restrict__ x,
    const float* __restrict__ ab1, const float* __restrict__ gb1,
    const float* __restrict__ ab2, const float* __restrict__ gb2,
    unsigned short* __restrict__ wProj, unsigned short* __restrict__ wGru,
    unsigned short* __restrict__ wEng,  unsigned short* __restrict__ wW2,
    float* __restrict__ xcat, float* __restrict__ wlast,
    float* __restrict__ b2diff)
{
  int b = blockIdx.x, t = threadIdx.x;
  if (b < 2048){
    int i = b*256 + t; int r = (i*4)>>11, c = (i*4)&2047;
    pack4(proj_W + (size_t)r*2048 + c, wProj + (size_t)r*2048 + c, 1.0f);
  } else if (b < 6656){
    int i = (b-2048)*256 + t; int row = (i*4)/1536, c = (i*4)%1536;
    const float* s = (c < 512) ? (Wih + (size_t)row*(OD+1) + c)
                               : (Whh + (size_t)row*HD + (c-512));
    pack4(s, wGru + (size_t)row*1536 + c, 1.0f);
  } else if (b < 6784){
    int i = (b-6656)*256 + t; int r = (i*4)>>10, c = (i*4)&1023;
    pack4(aW1 + (size_t)r*(ID+HD) + ID + c, wEng + (size_t)r*1024 + c, 1.0f);
  } else if (b < 6912){
    int i = (b-6784)*256 + t; int r = (i*4)>>10, c = (i*4)&1023;
    pack4(gW1 + (size_t)r*(ID+HD) + ID + c, wEng + 128*1024 + (size_t)r*1024 + c, 1.0f);
  } else if (b < 6976){
    int i = (b-6912)*256 + t; int r = (i*4)>>7, c = (i*4)&127;
    pack4(aW2 + (size_t)r*128 + c, wW2 + (size_t)r*256 + c, 1.0f);
  } else if (b < 7040){
    int i = (b-6976)*256 + t; int r = (i*4)>>7, c = (i*4)&127;
    pack4(gW2 + (size_t)r*128 + c, wW2 + (size_t)r*256 + 128 + c, -1.0f);
  } else if (b == 7040){
    const float* W  = (t < 128) ? aW1 : gW1;
    const float* bb = (t < 128) ? ab1 : gb1;
    int n = t & 127;
    float s = bb[n];
    const float* wr = W + (size_t)n*(ID+HD);
    for (int k=0;k<ID;k++) s += x[k]*wr[k];
    xcat[t] = s;
  } else {
    for (int n=t; n<3*HD; n+=256) wlast[n] = Wih[(size_t)n*(OD+1) + OD];
    for (int n=t; n<OD;   n+=256) b2diff[n] = ab2[n] - gb2[n];
  }
}

// ---------------------------------------------------------------------------
// K1: decohere features -> bf16 feat[NC][2HD]
__global__ __launch_bounds__(256) void k_feat(
    const float* __restrict__ rho_diag, const float* __restrict__ noise_diag,
    const float* __restrict__ rho_off,  const float* __restrict__ gamma,
    unsigned short* __restrict__ featb)
{
  int row = blockIdx.x;
  int t = threadIdx.x;
  float g = 1.0f/(1.0f+__expf(-gamma[0]));
  const float* rd = rho_diag  + (size_t)row*HD;
  const float* nd = noise_diag+ (size_t)row*HD;
  const float* ro = rho_off   + (size_t)row*HD;
  unsigned short* f0 = featb + (size_t)row*(2*HD);

  float v[4];
  float mx = -1e30f;
  for (int i=0;i<4;i++){ int j=t+i*256; v[i] = rd[j] + nd[j]*g*0.1f; mx = fmaxf(mx, v[i]); }
  __shared__ float red[256];
  red[t]=mx; __syncthreads();
  for(int s=128;s>0;s>>=1){ if(t<s) red[t]=fmaxf(red[t],red[t+s]); __syncthreads(); }
  mx = red[0]; __syncthreads();
  float sm=0.0f;
  for(int i=0;i<4;i++){ v[i]=__expf(v[i]-mx); sm+=v[i]; }
  red[t]=sm; __syncthreads();
  for(int s=128;s>0;s>>=1){ if(t<s) red[t]+=red[t+s]; __syncthreads(); }
  float inv = 1.0f/red[0];
  float om_g = 1.0f - g;
  for(int i=0;i<4;i++){
    int j=t+i*256;
    f0[j]     = f2bf(v[i]*inv);
    f0[HD+j]  = f2bf(fabsf(ro[j])*om_g);
  }
}

// ---------------------------------------------------------------------------
// MFMA bf16 GEMM: 128x128 tile, BK=32, 4 waves, 3-buffer counted-vmcnt pipeline.
// MODE 0: v = e0[m*N+n] + 0.1*(acc + e1[n]); write Cb only     (inj -> h bf16)
// MODE 1: v = relu(acc + e0[n]);            write Cb only      (engine hidden)
// MODE 2: v = acc + e0[n];                  write Cf + Cb      (out)
template<int MODE>
__global__ __launch_bounds__(256) void k_mgemm(
    const unsigned short* __restrict__ A, int lda,
    const unsigned short* __restrict__ W,
    int K, int N,
    float* __restrict__ Cf, int ldcf,
    unsigned short* __restrict__ Cb, int ldcb,
    const float* __restrict__ e0, const float* __restrict__ e1)
{
  __shared__ __attribute__((aligned(16))) unsigned short Asb[3][128*32];
  __shared__ __attribute__((aligned(16))) unsigned short Bsb[3][128*32];
  const int t = threadIdx.x;
  const int lane = t & 63, wid = t >> 6;
  const int wr = wid >> 1, wc = wid & 1;

  // n-major XCD chunked swizzle (all grids have nwg % 8 == 0)
  const int nwg = gridDim.x*gridDim.y;
  const int bid = blockIdx.y*gridDim.x + blockIdx.x;
  const int swz = (bid & 7)*(nwg >> 3) + (bid >> 3);
  const int n0 = (swz / gridDim.y) * 128, m0 = (swz % gridDim.y) * 128;

  const int srow = lane >> 2;
  const int skch = (lane & 3) * 8;
  const int fr = lane & 15, fk = (lane >> 4) * 8;

  const int nk = K >> 5;
  f32x4 acc[4][4] = {};

  auto STAGE = [&](int kc, int bf){
    const int k0 = kc << 5;
    for (int q = 0; q < 2; ++q) {
      int r = wid*32 + q*16 + srow;
      gload16(A + (size_t)(m0 + r)*lda + k0 + skch, &Asb[bf][(wid*32 + q*16)*32]);
      gload16(W + (size_t)(n0 + r)*K   + k0 + skch, &Bsb[bf][(wid*32 + q*16)*32]);
    }
  };

  STAGE(0, 0);
  if (nk > 1) { STAGE(1, 1); WAIT_VM4(); } else { WAIT_VM0(); }
  BARRIER();

  for (int kk = 0; kk < nk; ++kk) {
    const int buf = kk % 3;
    if (kk + 2 < nk) STAGE(kk + 2, (kk + 2) % 3);
    const unsigned short* Ab = &Asb[buf][0];
    const unsigned short* Bb = &Bsb[buf][0];
    bf16x8 af[4], bfr[4];
    #pragma unroll
    for (int i = 0; i < 4; ++i)
      af[i]  = *reinterpret_cast<const bf16x8*>(&Ab[(wr*64 + i*16 + fr)*32 + fk]);
    #pragma unroll
    for (int j = 0; j < 4; ++j)
      bfr[j] = *reinterpret_cast<const bf16x8*>(&Bb[(wc*64 + j*16 + fr)*32 + fk]);
    #pragma unroll
    for (int i = 0; i < 4; ++i)
      #pragma unroll
      for (int j = 0; j < 4; ++j)
        acc[i][j] = __builtin_amdgcn_mfma_f32_16x16x32_bf16(af[i], bfr[j], acc[i][j], 0, 0, 0);
    if (kk + 1 < nk) {
      if (kk + 2 < nk) WAIT_VM4(); else WAIT_VM0();
      BARRIER();
    }
  }

  const int cr = (lane >> 4) * 4;
  const int cc = lane & 15;
  for (int i = 0; i < 4; ++i){
    for (int j = 0; j < 4; ++j){
      for (int r = 0; r < 4; ++r){
        int m = m0 + wr*64 + i*16 + cr + r;
        int n = n0 + wc*64 + j*16 + cc;
        float v = acc[i][j][r];
        if (MODE == 0)      v = e0[(size_t)m*N + n] + 0.1f*(v + e1[n]);
        else if (MODE == 1) v = fmaxf(v + e0[n], 0.0f);
        else if (MODE == 2) v = v + e0[n];
        if (MODE == 2) Cf[(size_t)m*ldcf + n] = v;
        Cb[(size_t)m*ldcb + n] = f2bf(v);
      }
    }
  }
}

// ---------------------------------------------------------------------------
// GRU megakernel: 64x64 tile, 4 waves, BK=32, 3-buffer counted-vmcnt pipeline.
// Acat[NC][1536] = [out(512) | h(1024)] bf16; Wg[3][1024][1536] gate-cat.
__global__ __launch_bounds__(256) void k_gru_mega(
    const unsigned short* __restrict__ Acat,
    const unsigned short* __restrict__ Wg,
    const float* __restrict__ bih, const float* __restrict__ bhh,
    const float* __restrict__ tens, const float* __restrict__ wlast,
    float* __restrict__ newh)
{
  __shared__ __attribute__((aligned(16))) unsigned short As[3][64*32];
  __shared__ __attribute__((aligned(16))) unsigned short Rs[3][64*32];
  __shared__ __attribute__((aligned(16))) unsigned short Zs[3][64*32];
  __shared__ __attribute__((aligned(16))) unsigned short Ns[3][64*32];
  const int t = threadIdx.x;
  const int lane = t & 63, wid = t >> 6;
  const int wr = wid >> 1, wc = wid & 1;

  // round-5 blocked swizzle (measured FETCH=164MB): grid (16,128), nwg=2048
  const int nwg = gridDim.x*gridDim.y;
  const int bid = blockIdx.y*gridDim.x + blockIdx.x;
  const int swz = (bid & 7)*(nwg >> 3) + (bid >> 3);
  const int m0 = (swz >> 4) * 64, n0 = (swz & 15) * 64;

  const int srow = lane >> 2;          // 0..15
  const int skch = (lane & 3) * 8;
  const int fr = lane & 15, fk = (lane >> 4) * 8;

  // wave w stages matrix w (A, Wr, Wz, Wn)
  const unsigned short* sbase;
  unsigned short* lb;
  if      (wid == 0){ sbase = Acat + (size_t)m0*1536;          lb = &As[0][0]; }
  else if (wid == 1){ sbase = Wg   + (size_t)n0*1536;          lb = &Rs[0][0]; }
  else if (wid == 2){ sbase = Wg + (size_t)(HD   + n0)*1536;   lb = &Zs[0][0]; }
  else              { sbase = Wg + (size_t)(2*HD + n0)*1536;   lb = &Ns[0][0]; }

  f32x4 acc_r[2][2] = {}, acc_z[2][2] = {}, acc_na[2][2] = {}, acc_nb[2][2] = {};

  auto STAGE = [&](int kc, int bf){
    const int k0 = kc << 5;
    #pragma unroll
    for (int q = 0; q < 4; ++q)
      gload16(sbase + (size_t)(q*16 + srow)*1536 + k0 + skch,
              lb + bf*(64*32) + (q*16)*32);
  };

  STAGE(0, 0);
  STAGE(1, 1);
  WAIT_VM4();
  BARRIER();

  const int nk = 48;
  for (int kk = 0; kk < nk; ++kk) {
    const int buf = kk % 3;
    if (kk + 2 < nk) STAGE(kk + 2, (kk + 2) % 3);
    const unsigned short* Ab = &As[0][0] + buf*(64*32);
    const unsigned short* Rb = &Rs[0][0] + buf*(64*32);
    const unsigned short* Zb = &Zs[0][0] + buf*(64*32);
    const unsigned short* Nb = &Ns[0][0] + buf*(64*32);
    bf16x8 af[2], br[2], bz[2], bn[2];
    #pragma unroll
    for (int i = 0; i < 2; ++i)
      af[i] = *reinterpret_cast<const bf16x8*>(&Ab[(wr*32 + i*16 + fr)*32 + fk]);
    #pragma unroll
    for (int j = 0; j < 2; ++j){
      br[j] = *reinterpret_cast<const bf16x8*>(&Rb[(wc*32 + j*16 + fr)*32 + fk]);
      bz[j] = *reinterpret_cast<const bf16x8*>(&Zb[(wc*32 + j*16 + fr)*32 + fk]);
      bn[j] = *reinterpret_cast<const bf16x8*>(&Nb[(wc*32 + j*16 + fr)*32 + fk]);
    }
    if (kk < 16){
      #pragma unroll
      for (int i = 0; i < 2; ++i)
        #pragma unroll
        for (int j = 0; j < 2; ++j){
          acc_r [i][j] = __builtin_amdgcn_mfma_f32_16x16x32_bf16(af[i], br[j], acc_r [i][j], 0,0,0);
          acc_z [i][j] = __builtin_amdgcn_mfma_f32_16x16x32_bf16(af[i], bz[j], acc_z [i][j], 0,0,0);
          acc_na[i][j] = __builtin_amdgcn_mfma_f32_16x16x32_bf16(af[i], bn[j], acc_na[i][j], 0,0,0);
        }
    } else {
      #pragma unroll
      for (int i = 0; i < 2; ++i)
        #pragma unroll
        for (int j = 0; j < 2; ++j){
          acc_r [i][j] = __builtin_amdgcn_mfma_f32_16x16x32_bf16(af[i], br[j], acc_r [i][j], 0,0,0);
          acc_z [i][j] = __builtin_amdgcn_mfma_f32_16x16x32_bf16(af[i], bz[j], acc_z [i][j], 0,0,0);
          acc_nb[i][j] = __builtin_amdgcn_mfma_f32_16x16x32_bf16(af[i], bn[j], acc_nb[i][j], 0,0,0);
        }
    }
    if (kk + 1 < nk) {
      if (kk + 2 < nk) WAIT_VM4(); else WAIT_VM0();
      BARRIER();
    }
  }

  const int cr = (lane >> 4) * 4;
  const int cc = lane & 15;
  for (int i = 0; i < 2; ++i){
    for (int r = 0; r < 4; ++r){
      int m = m0 + wr*32 + i*16 + cr + r;
      float tm = tens[m];
      for (int j = 0; j < 2; ++j){
        int n = n0 + wc*32 + j*16 + cc;
        float sr  = acc_r [i][j][r] + bih[n]      + tm*wlast[n]      + bhh[n];
        float sz  = acc_z [i][j][r] + bih[HD+n]   + tm*wlast[HD+n]   + bhh[HD+n];
        float sni = acc_na[i][j][r] + bih[2*HD+n] + tm*wlast[2*HD+n];
        float snh = acc_nb[i][j][r] + bhh[2*HD+n];
        float rg = sigmf(sr);
        float zg = sigmf(sz);
        float nn = tanhf(sni + rg*snh);
        float hv = bf2f(Acat[(size_t)m*1536 + 512 + n]);
        newh[(size_t)m*HD + n] = (1.0f - zg)*nn + zg*hv;
      }
    }
  }
}

// ---------------------------------------------------------------------------
__global__ __launch_bounds__(256) void k_tension(
    const float* __restrict__ outp, float* __restrict__ tens)
{
  int m = blockIdx.x, t = threadIdx.x;
  float s = 0.0f;
  for (int j=t;j<OD;j+=256){ float v = outp[(size_t)m*OD + j]; s += v*v; }
  __shared__ float red[256];
  red[t]=s; __syncthreads();
  for(int k=128;k>0;k>>=1){ if(t<k) red[t]+=red[t+k]; __syncthreads(); }
  if (t==0) tens[m] = red[0] * (1.0f/OD);
}

// ---------------------------------------------------------------------------
__global__ __launch_bounds__(256) void k_fmean(
    const float* __restrict__ newh, float* __restrict__ fmean)
{
  int f = blockIdx.x;
  int j = blockIdx.y*256 + threadIdx.x;
  const float* base = newh + (size_t)f*FS*HD + j;
  float s = 0.0f;
  for (int c=0;c<FS;c++) s += base[(size_t)c*HD];
  fmean[f*HD + j] = s * (1.0f/FS);
}

__global__ __launch_bounds__(256) void k_sync(
    float* __restrict__ newh, const float* __restrict__ fmean,
    const int* __restrict__ step)
{
  size_t idx = (size_t)blockIdx.x*256 + threadIdx.x;
  int cell = (int)(idx / HD);
  int j    = (int)(idx % HD);
  int f = cell / FS, c = cell % FS;
  float v = newh[idx];
  v = 0.85f*v + 0.15f*fmean[f*HD + j];
  if (step[0] > 5 && c < DC){
    float glob = 0.0f;
    for (int ff=0; ff<NF; ff++) glob += fmean[ff*HD + j];
    glob *= (1.0f/NF);
    v = 0.85f*v + 0.15f*glob;
  }
  newh[idx] = v;
}

__global__ __launch_bounds__(1024) void k_wstats(
    const float* __restrict__ tens, float* __restrict__ stats)
{
  int t = threadIdx.x;
  float mx = -1e30f;
  for (int i=t;i<NC;i+=1024) mx = fmaxf(mx, tens[i]);
  __shared__ float red[1024];
  red[t]=mx; __syncthreads();
  for(int s=512;s>0;s>>=1){ if(t<s) red[t]=fmaxf(red[t],red[t+s]); __syncthreads(); }
  mx = red[0]; __syncthreads();
  float sm=0.0f;
  for (int i=t;i<NC;i+=1024) sm += __expf(tens[i]-mx);
  red[t]=sm; __syncthreads();
  for(int s=512;s>0;s>>=1){ if(t<s) red[t]+=red[t+s]; __syncthreads(); }
  if (t==0){ stats[0]=mx; stats[1]=red[0]; }
}

__global__ __launch_bounds__(256) void k_wnorm(
    const float* __restrict__ tens, const float* __restrict__ stats,
    float* __restrict__ w)
{
  int m = blockIdx.x*256 + threadIdx.x;
  w[m] = __expf(tens[m]-stats[0]) * (1.0f/stats[1]);
}

__global__ __launch_bounds__(256) void k_comb1(
    const float* __restrict__ outp, const float* __restrict__ w,
    float* __restrict__ partial)
{
  int b = blockIdx.x, t = threadIdx.x;
  float a0 = 0.0f, a1 = 0.0f;
  for (int m = 0; m < 128; ++m){
    int row = b*128 + m;
    float wm = w[row];
    const float* r = outp + (size_t)row*OD;
    a0 += wm * r[t];
    a1 += wm * r[t+256];
  }
  partial[(size_t)b*OD + t]       = a0;
  partial[(size_t)b*OD + t + 256] = a1;
}

__global__ __launch_bounds__(256) void k_comb2(
    const float* __restrict__ partial, float* __restrict__ comb)
{
  int n = blockIdx.x*256 + threadIdx.x;
  float s = 0.0f;
  for (int b = 0; b < 64; ++b) s += partial[(size_t)b*OD + n];
  comb[n] = s;
}

__global__ __launch_bounds__(128) void k_pred(
    const float* __restrict__ comb, const float* __restrict__ headW,
    const float* __restrict__ headb, float* __restrict__ pred)
{
  int i = blockIdx.x, t = threadIdx.x;
  float s = 0.0f;
  const float* wr = headW + (size_t)i*OD;
  for (int k=t;k<OD;k+=128) s += comb[k]*wr[k];
  __shared__ float red[128];
  red[t]=s; __syncthreads();
  for (int sx=64;sx>0;sx>>=1){ if(t<sx) red[t]+=red[t+sx]; __syncthreads(); }
  if (t==0) pred[i] = red[0] + headb[i];
}

// ---------------------------------------------------------------------------
extern "C" void kernel_launch(void* const* d_in, const int* in_sizes, int n_in,
                              void* d_out, int out_size, void* d_ws, size_t ws_size,
                              hipStream_t stream)
{
  const float* x        = (const float*)d_in[0];
  const float* rho_diag = (const float*)d_in[1];
  const float* rho_off  = (const float*)d_in[2];
  const float* hiddens  = (const float*)d_in[3];
  const float* gamma    = (const float*)d_in[4];
  const float* proj_W   = (const float*)d_in[5];
  const float* proj_b   = (const float*)d_in[6];
  const float* a_W1     = (const float*)d_in[7];
  const float* a_b1     = (const float*)d_in[8];
  const float* a_W2     = (const float*)d_in[9];
  const float* a_b2     = (const float*)d_in[10];
  const float* g_W1     = (const float*)d_in[11];
  const float* g_b1     = (const float*)d_in[12];
  const float* g_W2     = (const float*)d_in[13];
  const float* g_b2     = (const float*)d_in[14];
  const float* gru_Wih  = (const float*)d_in[15];
  const float* gru_bih  = (const float*)d_in[16];
  const float* gru_Whh  = (const float*)d_in[17];
  const float* gru_bhh  = (const float*)d_in[18];
  const float* head_W   = (const float*)d_in[19];
  const float* head_b   = (const float*)d_in[20];
  const float* noise_d  = (const float*)d_in[21];
  const int*   step     = (const int*)d_in[23];

  float* pred = (float*)d_out;                  // [512]
  float* newh = (float*)d_out + ID;             // [NC*HD]

  char* ws = (char*)d_ws;
  const size_t MB = 1024*1024;
  unsigned short* Acat   = (unsigned short*)(ws + 0);        // [NC][1536] 24MB
  unsigned short* featb  = (unsigned short*)(ws + 24*MB);    // [NC][2048] 32MB
  float*          outp_f = (float*)(ws + 56*MB);             // [NC][512] 16MB
  unsigned short* eag    = (unsigned short*)(ws + 72*MB);    // [NC][256]  4MB
  unsigned short* wProj  = (unsigned short*)(ws + 76*MB);    // [1024][2048] 4MB
  unsigned short* wGru   = (unsigned short*)(ws + 80*MB);    // [3][1024][1536] 9MB
  unsigned short* wEng   = (unsigned short*)(ws + 89*MB);    // [256][1024] 0.5MB
  unsigned short* wW2    = (unsigned short*)(ws + 89*MB + 512*1024); // [512][256] 0.25MB
  char* sm = ws + 90*MB;
  float* tens    = (float*)(sm + 0);          // [NC]
  float* xcat    = (float*)(sm + 64*1024);    // [256]
  float* wlast   = (float*)(sm + 128*1024);   // [3HD]
  float* b2diff  = (float*)(sm + 160*1024);   // [OD]
  float* fmean   = (float*)(sm + 192*1024);   // [NF*HD]
  float* stats   = (float*)(sm + 256*1024);   // [2]
  float* wts     = (float*)(sm + 320*1024);   // [NC]
  float* partial = (float*)(sm + 384*1024);   // [64][512] 128KB
  float* comb    = (float*)(sm + 576*1024);   // [OD]

  dim3 blk(256);

  // all conversions + xcat + wlast + b2diff in one launch
  k_prep<<<dim3(7042), blk, 0, stream>>>(
      proj_W, gru_Wih, gru_Whh, a_W1, g_W1, a_W2, g_W2, x,
      a_b1, g_b1, a_b2, g_b2, wProj, wGru, wEng, wW2, xcat, wlast, b2diff);
  // feat
  k_feat<<<dim3(NC), blk, 0, stream>>>(rho_diag, noise_d, rho_off, gamma, featb);

  // inj: h(bf16) = hiddens + 0.1*(feat@projW^T + b) -> Acat cols 512..1535
  k_mgemm<0><<<dim3(HD/128, NC/128), blk, 0, stream>>>(
      featb, 2*HD, wProj, 2*HD, HD, nullptr, 0, Acat + 512, 1536, hiddens, proj_b);
  // engine hidden: eag = relu(h@W1h^T + xcat)
  k_mgemm<1><<<dim3(256/128, NC/128), blk, 0, stream>>>(
      Acat + 512, 1536, wEng, HD, 256, nullptr, 0, eag, 256, xcat, nullptr);
  // out = eag@W2cat^T + (ab2-gb2) -> outp_f + Acat cols 0..511
  k_mgemm<2><<<dim3(OD/128, NC/128), blk, 0, stream>>>(
      eag, 256, wW2, 256, OD, outp_f, OD, Acat, 1536, b2diff, nullptr);
  // tension
  k_tension<<<dim3(NC), blk, 0, stream>>>(outp_f, tens);
  // fused gi+gh+GRU -> newh (64x64 tile, 4 waves, 3-buf pipeline)
  k_gru_mega<<<dim3(HD/64, NC/64), blk, 0, stream>>>(
      Acat, wGru, gru_bih, gru_bhh, tens, wlast, newh);
  // faction sync
  k_fmean<<<dim3(NF, HD/256), blk, 0, stream>>>(newh, fmean);
  k_sync<<<dim3((NC*HD)/256), blk, 0, stream>>>(newh, fmean, step);
  // tension softmax -> combined -> pred
  k_wstats<<<dim3(1), dim3(1024), 0, stream>>>(tens, stats);
  k_wnorm<<<dim3(NC/256), blk, 0, stream>>>(tens, stats, wts);
  k_comb1<<<dim3(64), blk, 0, stream>>>(outp_f, wts, partial);
  k_comb2<<<dim3(2), blk, 0, stream>>>(partial, comb);
  k_pred<<<dim3(ID), dim3(128), 0, stream>>>(comb, head_W, head_b, pred);
}